// Round 1
// baseline (492.347 us; speedup 1.0000x reference)
//
#include <hip/hip_runtime.h>

// SlotAttention MI355X (gfx950).
// Structure: k_init (slots init + fp16 weight casts) ; per iteration:
//   k_q (LN(slots)+q proj, zero accumulators) -> k_attn (fused LN/proj/attn,
//   MFMA fp16, streaming over tokens, atomics into acc/colsum) -> k_update
//   (GRU + LN + MLP per (b,s) row).
// HBM plan: inputs 134MB read once (iter0), x_ln fp16 64MB written once,
// read twice. No [B,N,S] attention matrix is ever materialized.

#define Bb 128
#define Nn 4096
#define Dd 64
#define Ss 7
#define Hh 128

typedef _Float16 f16;
typedef _Float16 f16x8 __attribute__((ext_vector_type(8)));
typedef _Float16 f16x4 __attribute__((ext_vector_type(4)));
typedef float    f32x4 __attribute__((ext_vector_type(4)));

#define LGKM0() asm volatile("s_waitcnt lgkmcnt(0)" ::: "memory")
#define CBAR()  asm volatile("" ::: "memory")

static __device__ __forceinline__ float dot4(f32x4 a, f32x4 b) {
  return a.x*b.x + a.y*b.y + a.z*b.z + a.w*b.w;
}

// ---------------------------------------------------------------- k_init ----
// blocks 0..223: slots = mu + exp(log_sigma)*noise  (57344 elements)
// blocks 224..239: Wk -> fp16 ; blocks 240..255: Wv -> fp16
__global__ __launch_bounds__(256) void k_init(
    const float* __restrict__ noise, const float* __restrict__ mu,
    const float* __restrict__ ls, const float* __restrict__ Wk,
    const float* __restrict__ Wv, float* __restrict__ slots,
    f16* __restrict__ Wk16, f16* __restrict__ Wv16)
{
  int bk = blockIdx.x, t = threadIdx.x;
  if (bk < 224) {
    int i = bk*256 + t;            // < 57344
    int d = i & 63;
    slots[i] = mu[d] + expf(ls[d]) * noise[i];
  } else if (bk < 240) {
    int j = (bk-224)*256 + t;      // < 4096
    Wk16[j] = (f16)Wk[j];
  } else {
    int j = (bk-240)*256 + t;
    Wv16[j] = (f16)Wv[j];
  }
}

// ------------------------------------------------------------------- k_q ----
// One block per batch b (512 threads). LN(slots) -> q = (s@Wq^T)*scale into
// qpad[b][16][64] fp16 (rows 7..15 zero). Also zeroes acc_g / cs_g for this b.
__global__ __launch_bounds__(512) void k_q(
    const float* __restrict__ slots, const float* __restrict__ lnw,
    const float* __restrict__ lnb, const float* __restrict__ Wq,
    f16* __restrict__ qpad, float* __restrict__ acc_g, float* __restrict__ cs_g)
{
  __shared__ __align__(16) float sl[448];
  __shared__ __align__(16) float sn[448];
  __shared__ float mm[7], rr[7];
  const int b = blockIdx.x, t = threadIdx.x;
  if (t < 448) sl[t] = slots[b*448 + t];
  __syncthreads();
  if (t < 7) {
    float s1 = 0.f, s2 = 0.f;
    for (int j = 0; j < 64; j++) { float x = sl[t*64+j]; s1 += x; s2 += x*x; }
    float m = s1*(1.f/64.f), v = s2*(1.f/64.f) - m*m;
    mm[t] = m; rr[t] = rsqrtf(v + 1e-5f);
  }
  __syncthreads();
  if (t < 448) {
    int s = t >> 6, d = t & 63;
    sn[t] = (sl[t] - mm[s]) * rr[s] * lnw[d] + lnb[d];
  }
  __syncthreads();
  if (t < 448) {
    int s = t >> 6, d = t & 63;
    float a = 0.f;
    #pragma unroll
    for (int jc = 0; jc < 16; jc++) {
      f32x4 w = *(const f32x4*)(Wq + d*64 + jc*4);
      f32x4 u = *(const f32x4*)(sn + s*64 + jc*4);
      a += dot4(w, u);
    }
    qpad[(b*16+s)*64 + d] = (f16)(a * 0.125f);   // scale = D^-0.5 = 1/8
  } else {
    int idx = t - 448;                            // 0..63
    for (int r = 0; r < 9; r++) qpad[(b*16+7+r)*64 + idx] = (f16)0.f;
  }
  acc_g[b*1024 + t]        = 0.f;
  acc_g[b*1024 + 512 + t]  = 0.f;
  if (t < 16) cs_g[b*16 + t] = 0.f;
}

// ----------------------------------------------------------------- k_attn ---
// grid (8, 128): blockIdx.y = b, blockIdx.x = token chunk (512 tokens/block).
// 4 waves, each owns 128 tokens (4 steps x 32 tokens, 2 subtiles of 16).
// iter0: read inputs fp32, LN, write x_ln fp16. else: read x_ln fp16.
// Per 16-token subtile: kT = Wk@x^T (C rows=kdim -> b64-packed into
// kbuf[token][dim]); v = x@Wv^T (C rows=token -> b64-packed into
// vtbuf[dim][token]); logits MFMA (A=kbuf rows, B=q rows); softmax over
// slots across 16-lane groups (+EPS); P -> pbuf[slot][token] (b64 pack).
// Per 32 tokens: PV MFMA (A=pbuf, B=vtbuf) accumulates acc[slot][dim].
__global__ __launch_bounds__(256) void k_attn(
    const float* __restrict__ x_in, f16* __restrict__ xln,
    const f16* __restrict__ Wk16, const f16* __restrict__ Wv16,
    const f16* __restrict__ qpad,
    const float* __restrict__ lnw, const float* __restrict__ lnb,
    float* __restrict__ acc_g, float* __restrict__ cs_g, int iter0)
{
  __shared__ __align__(16) float accbuf[1024];
  __shared__ __align__(16) float csl[16];
  __shared__ __align__(16) f16 kbuf [4][16*72];
  __shared__ __align__(16) f16 vtbuf[4][64*40];
  __shared__ __align__(16) f16 pbuf [4][16*40];
  __shared__ __align__(16) f16 xbuf [4][16*72];

  const int b = blockIdx.y, cx = blockIdx.x;
  const int tid = threadIdx.x;
  const int w = tid >> 6, lane = tid & 63, quad = lane >> 4, col = lane & 15;

  #pragma unroll
  for (int p = 0; p < 4; p++) accbuf[p*256 + tid] = 0.f;
  if (tid < 16) csl[tid] = 0.f;
  __syncthreads();

  // Persistent fragments: Wk rows (A for kT), Wv rows (B for v), q rows (B).
  f16x8 wkA[4][2], wvB[4][2];
  #pragma unroll
  for (int mc = 0; mc < 4; mc++)
    #pragma unroll
    for (int h = 0; h < 2; h++) {
      wkA[mc][h] = *(const f16x8*)(Wk16 + (mc*16+col)*64 + h*32 + quad*8);
      wvB[mc][h] = *(const f16x8*)(Wv16 + (mc*16+col)*64 + h*32 + quad*8);
    }
  f16x8 qf[2];
  #pragma unroll
  for (int h = 0; h < 2; h++)
    qf[h] = *(const f16x8*)(qpad + (b*16+col)*64 + h*32 + quad*8);

  f32x4 zero4 = {0.f, 0.f, 0.f, 0.f};
  f32x4 acc[4];
  #pragma unroll
  for (int nc = 0; nc < 4; nc++) acc[nc] = zero4;
  float csum = 0.f;

  f32x4 w4 = {1.f,1.f,1.f,1.f}, b4 = {0.f,0.f,0.f,0.f};
  if (iter0) {
    w4 = *(const f32x4*)(lnw + col*4);
    b4 = *(const f32x4*)(lnb + col*4);
  }

  const size_t tok0 = (size_t)b*Nn + (size_t)cx*512 + (size_t)w*128;

  for (int step = 0; step < 4; step++) {
    #pragma unroll
    for (int st = 0; st < 2; st++) {
      const size_t tt = tok0 + step*32 + st*16;   // 16-token tile base
      f16x8 xf[2];
      if (iter0) {
        // lane layout: token = c*4+quad, dims col*4..+3 ; LN across col group
        #pragma unroll
        for (int c = 0; c < 4; c++) {
          int trow = c*4 + quad;
          f32x4 xv = *(const f32x4*)(x_in + (tt+trow)*64 + col*4);
          float s1 = xv.x+xv.y+xv.z+xv.w;
          float s2 = xv.x*xv.x + xv.y*xv.y + xv.z*xv.z + xv.w*xv.w;
          #pragma unroll
          for (int m = 1; m < 16; m <<= 1) {
            s1 += __shfl_xor(s1, m, 64);
            s2 += __shfl_xor(s2, m, 64);
          }
          float mean = s1*(1.f/64.f);
          float var  = s2*(1.f/64.f) - mean*mean;
          float rstd = rsqrtf(var + 1e-5f);
          f16x4 xo;
          xo.x = (f16)((xv.x-mean)*rstd*w4.x + b4.x);
          xo.y = (f16)((xv.y-mean)*rstd*w4.y + b4.y);
          xo.z = (f16)((xv.z-mean)*rstd*w4.z + b4.z);
          xo.w = (f16)((xv.w-mean)*rstd*w4.w + b4.w);
          *(f16x4*)&xbuf[w][trow*72 + col*4] = xo;
          *(f16x4*)(xln + (tt+trow)*64 + col*4) = xo;   // persist for iters 1,2
        }
        LGKM0();
        #pragma unroll
        for (int h = 0; h < 2; h++)
          xf[h] = *(const f16x8*)&xbuf[w][col*72 + h*32 + quad*8];
        CBAR();
      } else {
        #pragma unroll
        for (int h = 0; h < 2; h++)
          xf[h] = *(const f16x8*)(xln + (tt+col)*64 + h*32 + quad*8);
      }

      // kT projection: D[m=kdim][n=token]; regs = 4 consecutive kdims
      #pragma unroll
      for (int mc = 0; mc < 4; mc++) {
        f32x4 c0 = zero4;
        c0 = __builtin_amdgcn_mfma_f32_16x16x32_f16(wkA[mc][0], xf[0], c0, 0,0,0);
        c0 = __builtin_amdgcn_mfma_f32_16x16x32_f16(wkA[mc][1], xf[1], c0, 0,0,0);
        f16x4 kp; kp.x=(f16)c0.x; kp.y=(f16)c0.y; kp.z=(f16)c0.z; kp.w=(f16)c0.w;
        *(f16x4*)&kbuf[w][col*72 + mc*16 + quad*4] = kp;
      }
      // v projection: D[m=token][n=vdim]; regs = 4 consecutive tokens
      #pragma unroll
      for (int nc = 0; nc < 4; nc++) {
        f32x4 c0 = zero4;
        c0 = __builtin_amdgcn_mfma_f32_16x16x32_f16(xf[0], wvB[nc][0], c0, 0,0,0);
        c0 = __builtin_amdgcn_mfma_f32_16x16x32_f16(xf[1], wvB[nc][1], c0, 0,0,0);
        f16x4 vp; vp.x=(f16)c0.x; vp.y=(f16)c0.y; vp.z=(f16)c0.z; vp.w=(f16)c0.w;
        *(f16x4*)&vtbuf[w][(nc*16+col)*40 + st*16 + quad*4] = vp;
      }
      LGKM0();
      f16x8 kf[2];
      #pragma unroll
      for (int h = 0; h < 2; h++)
        kf[h] = *(const f16x8*)&kbuf[w][col*72 + h*32 + quad*8];
      CBAR();

      // logits: D[m=token][n=slot]; lane holds 4 tokens for slot=col
      f32x4 lg = zero4;
      lg = __builtin_amdgcn_mfma_f32_16x16x32_f16(kf[0], qf[0], lg, 0,0,0);
      lg = __builtin_amdgcn_mfma_f32_16x16x32_f16(kf[1], qf[1], lg, 0,0,0);

      const bool valid = (col < 7);
      f16x4 pp;
      #pragma unroll
      for (int r = 0; r < 4; r++) {
        float L  = valid ? lg[r] : -1e30f;
        float mx = L;
        #pragma unroll
        for (int m = 1; m < 16; m <<= 1) mx = fmaxf(mx, __shfl_xor(mx, m, 64));
        float e  = valid ? __expf(L - mx) : 0.f;
        float sm = e;
        #pragma unroll
        for (int m = 1; m < 16; m <<= 1) sm += __shfl_xor(sm, m, 64);
        float p = e * (1.f/sm) + (valid ? 1e-8f : 0.f);
        csum += p;
        pp[r] = (f16)p;
      }
      *(f16x4*)&pbuf[w][col*40 + st*16 + quad*4] = pp;
    }

    // PV over 32 tokens: A = P^T[slot][tok], B = V^T[dim][tok]
    LGKM0();
    f16x8 pf = *(const f16x8*)&pbuf[w][col*40 + quad*8];
    f16x8 vf[4];
    #pragma unroll
    for (int nc = 0; nc < 4; nc++)
      vf[nc] = *(const f16x8*)&vtbuf[w][(nc*16+col)*40 + quad*8];
    CBAR();
    #pragma unroll
    for (int nc = 0; nc < 4; nc++)
      acc[nc] = __builtin_amdgcn_mfma_f32_16x16x32_f16(pf, vf[nc], acc[nc], 0,0,0);
    CBAR();
  }

  // block reduce (LDS fp32 atomics), then device-scope atomics to global
  #pragma unroll
  for (int nc = 0; nc < 4; nc++)
    #pragma unroll
    for (int r = 0; r < 4; r++)
      __hip_atomic_fetch_add(&accbuf[(quad*4+r)*64 + nc*16 + col], acc[nc][r],
                             __ATOMIC_RELAXED, __HIP_MEMORY_SCOPE_WORKGROUP);
  __hip_atomic_fetch_add(&csl[col], csum,
                         __ATOMIC_RELAXED, __HIP_MEMORY_SCOPE_WORKGROUP);
  __syncthreads();
  #pragma unroll
  for (int p = 0; p < 4; p++)
    __hip_atomic_fetch_add(&acc_g[b*1024 + p*256 + tid], accbuf[p*256 + tid],
                           __ATOMIC_RELAXED, __HIP_MEMORY_SCOPE_AGENT);
  if (tid < 16)
    __hip_atomic_fetch_add(&cs_g[b*16 + tid], csl[tid],
                           __ATOMIC_RELAXED, __HIP_MEMORY_SCOPE_AGENT);
}

// --------------------------------------------------------------- k_update ---
// one wave per (b,s): updates = acc/colsum ; GRU (torch) ; LN ; MLP ; slots
__global__ __launch_bounds__(64) void k_update(
    const float* __restrict__ acc_g, const float* __restrict__ cs_g,
    const float* __restrict__ W_ih, const float* __restrict__ W_hh,
    const float* __restrict__ b_ih, const float* __restrict__ b_hh,
    const float* __restrict__ lnw, const float* __restrict__ lnb,
    const float* __restrict__ W1, const float* __restrict__ b1,
    const float* __restrict__ W2, const float* __restrict__ b2,
    float* __restrict__ slots)
{
  __shared__ __align__(16) float updv[64];
  __shared__ __align__(16) float prevv[64];
  __shared__ __align__(16) float mlnv[64];
  __shared__ __align__(16) float hbuf[128];
  const int bs = blockIdx.x;
  const int b = bs / 7, s = bs - b*7;
  const int d = threadIdx.x;

  float cs   = cs_g[b*16 + s];
  float upd  = acc_g[(b*16+s)*64 + d] / cs;
  float prev = slots[(b*7+s)*64 + d];
  updv[d] = upd; prevv[d] = prev;
  __syncthreads();

  float air = b_ih[d], aiz = b_ih[64+d], ain = b_ih[128+d];
  float ahr = b_hh[d], ahz = b_hh[64+d], ahn = b_hh[128+d];
  #pragma unroll
  for (int jc = 0; jc < 16; jc++) {
    f32x4 u = *(const f32x4*)&updv[jc*4];
    f32x4 p = *(const f32x4*)&prevv[jc*4];
    air += dot4(*(const f32x4*)(W_ih + d*64        + jc*4), u);
    aiz += dot4(*(const f32x4*)(W_ih + (64+d)*64   + jc*4), u);
    ain += dot4(*(const f32x4*)(W_ih + (128+d)*64  + jc*4), u);
    ahr += dot4(*(const f32x4*)(W_hh + d*64        + jc*4), p);
    ahz += dot4(*(const f32x4*)(W_hh + (64+d)*64   + jc*4), p);
    ahn += dot4(*(const f32x4*)(W_hh + (128+d)*64  + jc*4), p);
  }
  float r = 1.f/(1.f + __expf(-(air+ahr)));
  float z = 1.f/(1.f + __expf(-(aiz+ahz)));
  float n = tanhf(ain + r*ahn);
  float hnew = (1.f - z)*n + z*prev;

  float s1 = hnew, s2 = hnew*hnew;
  #pragma unroll
  for (int m = 1; m < 64; m <<= 1) {
    s1 += __shfl_xor(s1, m, 64);
    s2 += __shfl_xor(s2, m, 64);
  }
  float mean = s1*(1.f/64.f), var = s2*(1.f/64.f) - mean*mean;
  float mln = (hnew - mean) * rsqrtf(var + 1e-5f) * lnw[d] + lnb[d];
  mlnv[d] = mln;
  __syncthreads();

  float h0 = b1[d], h1 = b1[64+d];
  #pragma unroll
  for (int jc = 0; jc < 16; jc++) {
    f32x4 m4 = *(const f32x4*)&mlnv[jc*4];
    h0 += dot4(*(const f32x4*)(W1 + d*64      + jc*4), m4);
    h1 += dot4(*(const f32x4*)(W1 + (64+d)*64 + jc*4), m4);
  }
  h0 = fmaxf(h0, 0.f); h1 = fmaxf(h1, 0.f);
  hbuf[d] = h0; hbuf[64+d] = h1;
  __syncthreads();

  float out = hnew + b2[d];
  #pragma unroll
  for (int hc = 0; hc < 32; hc++) {
    f32x4 hh = *(const f32x4*)&hbuf[hc*4];
    out += dot4(*(const f32x4*)(W2 + d*128 + hc*4), hh);
  }
  slots[(b*7+s)*64 + d] = out;
}

// ----------------------------------------------------------- kernel_launch --
extern "C" void kernel_launch(void* const* d_in, const int* in_sizes, int n_in,
                              void* d_out, int out_size, void* d_ws, size_t ws_size,
                              hipStream_t stream) {
  const float* inputs = (const float*)d_in[0];
  const float* noise  = (const float*)d_in[1];
  const float* ln_in_w = (const float*)d_in[2];
  const float* ln_in_b = (const float*)d_in[3];
  const float* ln_sl_w = (const float*)d_in[4];
  const float* ln_sl_b = (const float*)d_in[5];
  const float* ln_ml_w = (const float*)d_in[6];
  const float* ln_ml_b = (const float*)d_in[7];
  const float* mu = (const float*)d_in[8];
  const float* ls = (const float*)d_in[9];
  const float* Wq = (const float*)d_in[10];
  const float* Wk = (const float*)d_in[11];
  const float* Wv = (const float*)d_in[12];
  const float* W_ih = (const float*)d_in[13];
  const float* W_hh = (const float*)d_in[14];
  const float* b_ih = (const float*)d_in[15];
  const float* b_hh = (const float*)d_in[16];
  const float* W1 = (const float*)d_in[17];
  const float* b1 = (const float*)d_in[18];
  const float* W2 = (const float*)d_in[19];
  const float* b2 = (const float*)d_in[20];

  float* slots = (float*)d_out;     // [B,S,D] fp32, slots live here throughout

  // workspace layout (bytes)
  const size_t XLN_OFF  = 0;                   // fp16 [B,N,64]  = 64 MiB
  const size_t WK16_OFF = 67108864;            // fp16 [64,64]
  const size_t WV16_OFF = WK16_OFF + 8192;
  const size_t QPAD_OFF = WV16_OFF + 8192;     // fp16 [B,16,64]
  const size_t ACC_OFF  = QPAD_OFF + 262144;   // fp32 [B,16,64]
  const size_t CS_OFF   = ACC_OFF  + 524288;   // fp32 [B,16]
  const size_t NEED     = CS_OFF   + 8192;     // ~64.8 MiB
  if (ws_size < NEED) return;                  // would corrupt; fail visibly

  char* ws = (char*)d_ws;
  f16*   xln   = (f16*)(ws + XLN_OFF);
  f16*   Wk16  = (f16*)(ws + WK16_OFF);
  f16*   Wv16  = (f16*)(ws + WV16_OFF);
  f16*   qpad  = (f16*)(ws + QPAD_OFF);
  float* acc_g = (float*)(ws + ACC_OFF);
  float* cs_g  = (float*)(ws + CS_OFF);

  k_init<<<256, 256, 0, stream>>>(noise, mu, ls, Wk, Wv, slots, Wk16, Wv16);

  for (int it = 0; it < 3; it++) {
    k_q<<<128, 512, 0, stream>>>(slots, ln_sl_w, ln_sl_b, Wq, qpad, acc_g, cs_g);
    dim3 g(8, 128);
    k_attn<<<g, 256, 0, stream>>>(inputs, xln, Wk16, Wv16, qpad,
                                  ln_in_w, ln_in_b, acc_g, cs_g, it == 0 ? 1 : 0);
    k_update<<<896, 64, 0, stream>>>(acc_g, cs_g, W_ih, W_hh, b_ih, b_hh,
                                     ln_ml_w, ln_ml_b, W1, b1, W2, b2, slots);
  }
}

// Round 2
// 454.594 us; speedup vs baseline: 1.0830x; 1.0830x over previous
//
#include <hip/hip_runtime.h>

// SlotAttention MI355X (gfx950), round 2.
// logits = x @ (q@Wk)^T  (Wk folded into q per iteration -> no k projection).
// Transposed-logits softmax: D[slot][token], 2 shuffles per 16-token tile.
// Pipelined global loads; iter0 (fp32 LN + xln write) split into own kernel.
// k_gru: one block per batch (7 waves), fuses GRU+MLP+next-iter q/qk; all
// LDS traffic wave-local -> zero block barriers.

#define Nn 4096

typedef _Float16 f16;
typedef _Float16 f16x8 __attribute__((ext_vector_type(8)));
typedef _Float16 f16x4 __attribute__((ext_vector_type(4)));
typedef float    f32x4 __attribute__((ext_vector_type(4)));

#define LGKM0() asm volatile("s_waitcnt lgkmcnt(0)" ::: "memory")
#define CBAR()  asm volatile("" ::: "memory")

static __device__ __forceinline__ float dot4(f32x4 a, f32x4 b) {
  return a.x*b.x + a.y*b.y + a.z*b.z + a.w*b.w;
}

// ---------------------------------------------------------------- k_init ----
// blocks 0..223: slots = mu + exp(log_sigma)*noise ; 224..239: Wv -> fp16
__global__ __launch_bounds__(256) void k_init(
    const float* __restrict__ noise, const float* __restrict__ mu,
    const float* __restrict__ ls, const float* __restrict__ Wv,
    float* __restrict__ slots, f16* __restrict__ Wv16)
{
  int bk = blockIdx.x, t = threadIdx.x;
  if (bk < 224) {
    int i = bk*256 + t;
    int d = i & 63;
    slots[i] = mu[d] + expf(ls[d]) * noise[i];
  } else {
    int j = (bk-224)*256 + t;
    Wv16[j] = (f16)Wv[j];
  }
}

// ----------------------------------------------------------------- k_gru ----
// One block per batch b; 448 threads = 7 waves, wave w == slot s, lane == d.
// do_gru: updates=acc/cs ; GRU ; LN ; MLP ; slots written.
// do_q  : LN(slots) -> q -> qk=(q*scale)@Wk -> qkpad fp16 ; zero acc/cs.
// All LDS stages are wave-local (s == wave) -> no __syncthreads needed.
__global__ __launch_bounds__(448) void k_gru(
    float* __restrict__ acc_g, float* __restrict__ cs_g,
    const float* __restrict__ W_ih, const float* __restrict__ W_hh,
    const float* __restrict__ b_ih, const float* __restrict__ b_hh,
    const float* __restrict__ lnm_w, const float* __restrict__ lnm_b,
    const float* __restrict__ W1, const float* __restrict__ b1,
    const float* __restrict__ W2, const float* __restrict__ b2,
    const float* __restrict__ lns_w, const float* __restrict__ lns_b,
    const float* __restrict__ Wq, const float* __restrict__ Wk,
    float* __restrict__ slots, f16* __restrict__ qkpad,
    int do_gru, int do_q)
{
  __shared__ __align__(16) float updv[448];
  __shared__ __align__(16) float prevv[448];
  __shared__ __align__(16) float mlnv[448];
  __shared__ __align__(16) float sn2[448];
  __shared__ __align__(16) float qv[448];
  __shared__ __align__(16) float hbuf[896];
  const int b = blockIdx.x, t = threadIdx.x;
  const int s = t >> 6, d = t & 63;

  float out;
  if (do_gru) {
    float cs   = cs_g[b*16 + s];
    float upd  = acc_g[(b*16+s)*64 + d] / cs;
    float prev = slots[(b*7+s)*64 + d];
    updv[t] = upd; prevv[t] = prev;

    float air = b_ih[d], aiz = b_ih[64+d], ain = b_ih[128+d];
    float ahr = b_hh[d], ahz = b_hh[64+d], ahn = b_hh[128+d];
    #pragma unroll
    for (int jc = 0; jc < 16; jc++) {
      f32x4 u = *(const f32x4*)&updv[s*64 + jc*4];
      f32x4 p = *(const f32x4*)&prevv[s*64 + jc*4];
      air += dot4(*(const f32x4*)(W_ih + d*64        + jc*4), u);
      aiz += dot4(*(const f32x4*)(W_ih + (64+d)*64   + jc*4), u);
      ain += dot4(*(const f32x4*)(W_ih + (128+d)*64  + jc*4), u);
      ahr += dot4(*(const f32x4*)(W_hh + d*64        + jc*4), p);
      ahz += dot4(*(const f32x4*)(W_hh + (64+d)*64   + jc*4), p);
      ahn += dot4(*(const f32x4*)(W_hh + (128+d)*64  + jc*4), p);
    }
    float r = 1.f/(1.f + __expf(-(air+ahr)));
    float z = 1.f/(1.f + __expf(-(aiz+ahz)));
    float n = tanhf(ain + r*ahn);
    float hnew = (1.f - z)*n + z*prev;

    float s1 = hnew, s2 = hnew*hnew;
    #pragma unroll
    for (int m = 1; m < 64; m <<= 1) {
      s1 += __shfl_xor(s1, m, 64);
      s2 += __shfl_xor(s2, m, 64);
    }
    float mean = s1*(1.f/64.f), var = s2*(1.f/64.f) - mean*mean;
    float mln = (hnew - mean) * rsqrtf(var + 1e-5f) * lnm_w[d] + lnm_b[d];
    mlnv[t] = mln;

    float h0 = b1[d], h1 = b1[64+d];
    #pragma unroll
    for (int jc = 0; jc < 16; jc++) {
      f32x4 m4 = *(const f32x4*)&mlnv[s*64 + jc*4];
      h0 += dot4(*(const f32x4*)(W1 + d*64      + jc*4), m4);
      h1 += dot4(*(const f32x4*)(W1 + (64+d)*64 + jc*4), m4);
    }
    h0 = fmaxf(h0, 0.f); h1 = fmaxf(h1, 0.f);
    hbuf[s*128 + d] = h0; hbuf[s*128 + 64 + d] = h1;

    out = hnew + b2[d];
    #pragma unroll
    for (int hc = 0; hc < 32; hc++) {
      f32x4 hh = *(const f32x4*)&hbuf[s*128 + hc*4];
      out += dot4(*(const f32x4*)(W2 + d*128 + hc*4), hh);
    }
    slots[(b*7+s)*64 + d] = out;
  } else {
    out = slots[(b*7+s)*64 + d];
  }

  if (do_q) {
    // LN(out) per slot == per wave
    float s1 = out, s2 = out*out;
    #pragma unroll
    for (int m = 1; m < 64; m <<= 1) {
      s1 += __shfl_xor(s1, m, 64);
      s2 += __shfl_xor(s2, m, 64);
    }
    float mean = s1*(1.f/64.f), var = s2*(1.f/64.f) - mean*mean;
    float sv = (out - mean) * rsqrtf(var + 1e-5f) * lns_w[d] + lns_b[d];
    sn2[t] = sv;

    float q = 0.f;
    #pragma unroll
    for (int jc = 0; jc < 16; jc++) {
      f32x4 u = *(const f32x4*)&sn2[s*64 + jc*4];
      q += dot4(*(const f32x4*)(Wq + d*64 + jc*4), u);
    }
    qv[t] = q * 0.125f;                       // scale = D^-0.5

    float qk = 0.f;
    #pragma unroll
    for (int dd = 0; dd < 64; dd++)
      qk += qv[s*64 + dd] * Wk[dd*64 + d];
    qkpad[(b*16+s)*64 + d] = (f16)qk;

    for (int i = t; i < 576; i += 448) qkpad[b*1024 + 448 + i] = (f16)0.f;
    for (int i = t; i < 1024; i += 448) acc_g[b*1024 + i] = 0.f;
    if (t < 16) cs_g[b*16 + t] = 0.f;
  }
}

// ---------------------------------------------------------------- k_attn ----
// grid (8,128): y=b, x=chunk of 512 tokens. 4 waves x 128 tokens (8 tiles).
// Per 16-token tile: logits MFMA (A=qk frag, B=x row-frag) -> D[slot][token]
// (lane: token=col, slots=quad*4+r) ; cheap softmax ; pbuf[slot][tok] b16
// scatter ; v-proj MFMA -> vtbuf[dim][tok]. Per 32 tokens: PV MFMA.
template<int ITER0>
__global__ __launch_bounds__(256) void k_attn_t(
    const float* __restrict__ x_in, f16* __restrict__ xln,
    const f16* __restrict__ Wv16, const f16* __restrict__ qkpad,
    const float* __restrict__ lnw, const float* __restrict__ lnb,
    float* __restrict__ acc_g, float* __restrict__ cs_g)
{
  __shared__ __align__(16) float accbuf[1024];
  __shared__ __align__(16) float csl[16];
  __shared__ __align__(16) f16 pbuf [4][16*40];
  __shared__ __align__(16) f16 vtbuf[4][64*40];
  __shared__ __align__(16) f16 xbuf [ITER0 ? 4 : 1][16*72];

  const int b = blockIdx.y, cx = blockIdx.x;
  const int tid = threadIdx.x;
  const int w = tid >> 6, lane = tid & 63, quad = lane >> 4, col = lane & 15;

  #pragma unroll
  for (int p = 0; p < 4; p++) accbuf[p*256 + tid] = 0.f;
  if (tid < 16) csl[tid] = 0.f;
  __syncthreads();

  f16x8 wvB[4][2];
  #pragma unroll
  for (int nc = 0; nc < 4; nc++)
    #pragma unroll
    for (int h = 0; h < 2; h++)
      wvB[nc][h] = *(const f16x8*)(Wv16 + (nc*16+col)*64 + h*32 + quad*8);
  f16x8 qkf[2];
  #pragma unroll
  for (int h = 0; h < 2; h++)
    qkf[h] = *(const f16x8*)(qkpad + (b*16+col)*64 + h*32 + quad*8);

  const f32x4 zero4 = {0.f, 0.f, 0.f, 0.f};
  f32x4 acc[4];
  #pragma unroll
  for (int nc = 0; nc < 4; nc++) acc[nc] = zero4;
  float csump[4] = {0.f, 0.f, 0.f, 0.f};

  const size_t tok0 = (size_t)b*Nn + (size_t)cx*512 + (size_t)w*128;

  f32x4 w4[4], b4[4];
  f32x4 xvn[4];
  f16x8 xfn[2];
  if constexpr (ITER0) {
    #pragma unroll
    for (int i = 0; i < 4; i++) {
      w4[i] = *(const f32x4*)(lnw + quad*16 + i*4);
      b4[i] = *(const f32x4*)(lnb + quad*16 + i*4);
      xvn[i] = *(const f32x4*)(x_in + (tok0+col)*64 + quad*16 + i*4);
    }
  } else {
    #pragma unroll
    for (int h = 0; h < 2; h++)
      xfn[h] = *(const f16x8*)(xln + (tok0+col)*64 + h*32 + quad*8);
  }

  #pragma unroll
  for (int t = 0; t < 8; t++) {
    const size_t tt = tok0 + t*16;
    const int st = t & 1;
    f16x8 xf[2];

    if constexpr (ITER0) {
      f32x4 xv[4];
      #pragma unroll
      for (int i = 0; i < 4; i++) xv[i] = xvn[i];
      if (t < 7)
        #pragma unroll
        for (int i = 0; i < 4; i++)
          xvn[i] = *(const f32x4*)(x_in + (tt+16+col)*64 + quad*16 + i*4);
      // LN across the 4 lanes sharing this token (quads)
      float s1 = 0.f, s2 = 0.f;
      #pragma unroll
      for (int i = 0; i < 4; i++) { s1 += xv[i].x+xv[i].y+xv[i].z+xv[i].w;
                                    s2 += dot4(xv[i], xv[i]); }
      s1 += __shfl_xor(s1, 16, 64); s1 += __shfl_xor(s1, 32, 64);
      s2 += __shfl_xor(s2, 16, 64); s2 += __shfl_xor(s2, 32, 64);
      float mean = s1*(1.f/64.f);
      float rstd = rsqrtf(s2*(1.f/64.f) - mean*mean + 1e-5f);
      f16x8 ho0, ho1;
      #pragma unroll
      for (int i = 0; i < 2; i++)
        #pragma unroll
        for (int c = 0; c < 4; c++)
          ho0[i*4+c] = (f16)((xv[i][c]-mean)*rstd*w4[i][c] + b4[i][c]);
      #pragma unroll
      for (int i = 2; i < 4; i++)
        #pragma unroll
        for (int c = 0; c < 4; c++)
          ho1[(i-2)*4+c] = (f16)((xv[i][c]-mean)*rstd*w4[i][c] + b4[i][c]);
      *(f16x8*)(xln + (tt+col)*64 + quad*16)     = ho0;
      *(f16x8*)(xln + (tt+col)*64 + quad*16 + 8) = ho1;
      *(f16x8*)&xbuf[w][col*72 + quad*16]     = ho0;
      *(f16x8*)&xbuf[w][col*72 + quad*16 + 8] = ho1;
      LGKM0();
      xf[0] = *(const f16x8*)&xbuf[w][col*72 + quad*8];
      xf[1] = *(const f16x8*)&xbuf[w][col*72 + 32 + quad*8];
      CBAR();
    } else {
      xf[0] = xfn[0]; xf[1] = xfn[1];
      if (t < 7)
        #pragma unroll
        for (int h = 0; h < 2; h++)
          xfn[h] = *(const f16x8*)(xln + (tt+16+col)*64 + h*32 + quad*8);
    }

    // logits: D[slot][token]; lane: token=col, slot=quad*4+r
    f32x4 lg = zero4;
    lg = __builtin_amdgcn_mfma_f32_16x16x32_f16(qkf[0], xf[0], lg, 0,0,0);
    lg = __builtin_amdgcn_mfma_f32_16x16x32_f16(qkf[1], xf[1], lg, 0,0,0);

    float mx = -1e30f;
    #pragma unroll
    for (int r = 0; r < 4; r++)
      mx = fmaxf(mx, (quad*4+r < 7) ? lg[r] : -1e30f);
    mx = fmaxf(mx, __shfl_xor(mx, 16, 64));
    float e[4], sml = 0.f;
    #pragma unroll
    for (int r = 0; r < 4; r++) {
      e[r] = (quad*4+r < 7) ? __expf(lg[r]-mx) : 0.f;
      sml += e[r];
    }
    float sm = sml + __shfl_xor(sml, 16, 64);
    float inv = 1.f/sm;                 // quads 2,3: unused (masked below)
    #pragma unroll
    for (int r = 0; r < 4; r++) {
      float p = (quad*4+r < 7) ? (e[r]*inv + 1e-8f) : 0.f;
      f16 ph = (f16)p;
      csump[r] += (float)ph;            // consistent with fp16 P used in PV
      pbuf[w][(quad*4+r)*40 + st*16 + col] = ph;
    }

    // v projection: D[token][vdim]; pack 4 tokens -> vtbuf[vdim][token]
    #pragma unroll
    for (int nc = 0; nc < 4; nc++) {
      f32x4 c0 = zero4;
      c0 = __builtin_amdgcn_mfma_f32_16x16x32_f16(xf[0], wvB[nc][0], c0, 0,0,0);
      c0 = __builtin_amdgcn_mfma_f32_16x16x32_f16(xf[1], wvB[nc][1], c0, 0,0,0);
      f16x4 vp; vp.x=(f16)c0.x; vp.y=(f16)c0.y; vp.z=(f16)c0.z; vp.w=(f16)c0.w;
      *(f16x4*)&vtbuf[w][(nc*16+col)*40 + st*16 + quad*4] = vp;
    }

    if (st) {   // PV over the last 32 tokens
      LGKM0();
      f16x8 pf = *(const f16x8*)&pbuf[w][col*40 + quad*8];
      f16x8 vf[4];
      #pragma unroll
      for (int nc = 0; nc < 4; nc++)
        vf[nc] = *(const f16x8*)&vtbuf[w][(nc*16+col)*40 + quad*8];
      CBAR();
      #pragma unroll
      for (int nc = 0; nc < 4; nc++)
        acc[nc] = __builtin_amdgcn_mfma_f32_16x16x32_f16(pf, vf[nc], acc[nc], 0,0,0);
      CBAR();
    }
  }

  // csum: reduce across the 16 token-columns, once per kernel
  #pragma unroll
  for (int m = 1; m < 16; m <<= 1)
    #pragma unroll
    for (int r = 0; r < 4; r++)
      csump[r] += __shfl_xor(csump[r], m, 64);
  if (col == 0) {
    #pragma unroll
    for (int r = 0; r < 4; r++) {
      int slot = quad*4 + r;
      if (slot < 7)
        __hip_atomic_fetch_add(&csl[slot], csump[r],
                               __ATOMIC_RELAXED, __HIP_MEMORY_SCOPE_WORKGROUP);
    }
  }

  #pragma unroll
  for (int nc = 0; nc < 4; nc++)
    #pragma unroll
    for (int r = 0; r < 4; r++)
      __hip_atomic_fetch_add(&accbuf[(quad*4+r)*64 + nc*16 + col], acc[nc][r],
                             __ATOMIC_RELAXED, __HIP_MEMORY_SCOPE_WORKGROUP);
  __syncthreads();
  #pragma unroll
  for (int p = 0; p < 4; p++)
    __hip_atomic_fetch_add(&acc_g[b*1024 + p*256 + tid], accbuf[p*256 + tid],
                           __ATOMIC_RELAXED, __HIP_MEMORY_SCOPE_AGENT);
  if (tid < 16)
    __hip_atomic_fetch_add(&cs_g[b*16 + tid], csl[tid],
                           __ATOMIC_RELAXED, __HIP_MEMORY_SCOPE_AGENT);
}

// ----------------------------------------------------------- kernel_launch --
extern "C" void kernel_launch(void* const* d_in, const int* in_sizes, int n_in,
                              void* d_out, int out_size, void* d_ws, size_t ws_size,
                              hipStream_t stream) {
  const float* inputs  = (const float*)d_in[0];
  const float* noise   = (const float*)d_in[1];
  const float* ln_in_w = (const float*)d_in[2];
  const float* ln_in_b = (const float*)d_in[3];
  const float* ln_sl_w = (const float*)d_in[4];
  const float* ln_sl_b = (const float*)d_in[5];
  const float* ln_ml_w = (const float*)d_in[6];
  const float* ln_ml_b = (const float*)d_in[7];
  const float* mu   = (const float*)d_in[8];
  const float* ls   = (const float*)d_in[9];
  const float* Wq   = (const float*)d_in[10];
  const float* Wk   = (const float*)d_in[11];
  const float* Wv   = (const float*)d_in[12];
  const float* W_ih = (const float*)d_in[13];
  const float* W_hh = (const float*)d_in[14];
  const float* b_ih = (const float*)d_in[15];
  const float* b_hh = (const float*)d_in[16];
  const float* W1 = (const float*)d_in[17];
  const float* b1 = (const float*)d_in[18];
  const float* W2 = (const float*)d_in[19];
  const float* b2 = (const float*)d_in[20];

  float* slots = (float*)d_out;

  const size_t XLN_OFF  = 0;                   // fp16 [B,N,64] = 64 MiB
  const size_t WV16_OFF = 67108864;            // fp16 [64,64]
  const size_t QK_OFF   = WV16_OFF + 8192;     // fp16 [B,16,64]
  const size_t ACC_OFF  = QK_OFF   + 262144;   // fp32 [B,16,64]
  const size_t CS_OFF   = ACC_OFF  + 524288;   // fp32 [B,16]
  const size_t NEED     = CS_OFF   + 8192;
  if (ws_size < NEED) return;

  char* ws = (char*)d_ws;
  f16*   xln   = (f16*)(ws + XLN_OFF);
  f16*   Wv16  = (f16*)(ws + WV16_OFF);
  f16*   qkpad = (f16*)(ws + QK_OFF);
  float* acc_g = (float*)(ws + ACC_OFF);
  float* cs_g  = (float*)(ws + CS_OFF);

  k_init<<<240, 256, 0, stream>>>(noise, mu, ls, Wv, slots, Wv16);
  k_gru<<<128, 448, 0, stream>>>(acc_g, cs_g, W_ih, W_hh, b_ih, b_hh,
                                 ln_ml_w, ln_ml_b, W1, b1, W2, b2,
                                 ln_sl_w, ln_sl_b, Wq, Wk, slots, qkpad,
                                 0, 1);
  dim3 g(8, 128);
  for (int it = 0; it < 3; it++) {
    if (it == 0)
      k_attn_t<1><<<g, 256, 0, stream>>>(inputs, xln, Wv16, qkpad,
                                         ln_in_w, ln_in_b, acc_g, cs_g);
    else
      k_attn_t<0><<<g, 256, 0, stream>>>(inputs, xln, Wv16, qkpad,
                                         ln_in_w, ln_in_b, acc_g, cs_g);
    k_gru<<<128, 448, 0, stream>>>(acc_g, cs_g, W_ih, W_hh, b_ih, b_hh,
                                   ln_ml_w, ln_ml_b, W1, b1, W2, b2,
                                   ln_sl_w, ln_sl_b, Wq, Wk, slots, qkpad,
                                   1, it < 2 ? 1 : 0);
  }
}

// Round 4
// 449.252 us; speedup vs baseline: 1.0959x; 1.0119x over previous
//
#include <hip/hip_runtime.h>

// SlotAttention MI355X (gfx950), round 4 (= round 3 + intrinsic-name fix).
// Fully register-resident attn hot loop:
//   logits L^T = x @ qk^T  (D-layout: slot=col, token=quad*4+r)
//   softmax: lane-local exp (no max-sub; |L| small), 16-lane butterfly sum
//   P is DIRECTLY the 16x16x16 A-frag; x^T B-frags via selector-MFMA transpose
//   PV: acc[slot][dim] += P @ x   (Wv factored out -> applied in k_gru)
// No LDS / lgkmcnt in the loop. acc double-buffered (gru zeroes the buffer
// the NEXT attn uses -> no read/zero race). qk = LN(slots) @ Mt where
// Mt = scale * Wk^T @ Wq precomputed in k_init.

#define Nn 4096

typedef _Float16 f16;
typedef _Float16 f16x8 __attribute__((ext_vector_type(8)));
typedef _Float16 f16x4 __attribute__((ext_vector_type(4)));
typedef float    f32x4 __attribute__((ext_vector_type(4)));

#define MFMA16(a,b,c) __builtin_amdgcn_mfma_f32_16x16x16f16(a,b,c,0,0,0)
#define MFMA32(a,b,c) __builtin_amdgcn_mfma_f32_16x16x32_f16(a,b,c,0,0,0)

#define LGKM0() asm volatile("s_waitcnt lgkmcnt(0)" ::: "memory")
#define CBAR()  asm volatile("" ::: "memory")

static __device__ __forceinline__ float dot4(f32x4 a, f32x4 b) {
  return a.x*b.x + a.y*b.y + a.z*b.z + a.w*b.w;
}

// ---------------------------------------------------------------- k_init ----
// blocks 0..223: slots = mu + exp(log_sigma)*noise
// blocks 224..239: Mt[d][e] = 0.125 * sum_dd Wk[dd][d]*Wq[dd][e]
__global__ __launch_bounds__(256) void k_init(
    const float* __restrict__ noise, const float* __restrict__ mu,
    const float* __restrict__ ls, const float* __restrict__ Wq,
    const float* __restrict__ Wk, float* __restrict__ slots,
    float* __restrict__ Mt)
{
  int bk = blockIdx.x, t = threadIdx.x;
  if (bk < 224) {
    int i = bk*256 + t;
    int d = i & 63;
    slots[i] = mu[d] + expf(ls[d]) * noise[i];
  } else {
    int idx = (bk-224)*256 + t;        // 0..4095
    int d = idx >> 6, e = idx & 63;
    float a = 0.f;
    for (int dd = 0; dd < 64; dd++)
      a += Wk[dd*64 + d] * Wq[dd*64 + e];
    Mt[idx] = a * 0.125f;              // fold scale = D^-0.5
  }
}

// ----------------------------------------------------------------- k_gru ----
// One wave per (b,s): 224 blocks x 4 waves = 896 waves. Wave-local LDS only.
// do_gru: Y=acc_rd row -> updates = (Y@Wv^T)/cs ; GRU ; LN ; MLP ; slots.
// do_q  : LN(slots) -> qk = sv @ Mt^T -> qkpad fp16 ; s==0 wave zeroes the
//         NEXT iteration's acc/cs buffers (acc_zw/cs_zw) + qkpad pad rows.
__global__ __launch_bounds__(256) void k_gru(
    const float* __restrict__ acc_rd, const float* __restrict__ cs_rd,
    float* __restrict__ acc_zw, float* __restrict__ cs_zw,
    const float* __restrict__ Wv,
    const float* __restrict__ W_ih, const float* __restrict__ W_hh,
    const float* __restrict__ b_ih, const float* __restrict__ b_hh,
    const float* __restrict__ lnm_w, const float* __restrict__ lnm_b,
    const float* __restrict__ W1, const float* __restrict__ b1,
    const float* __restrict__ W2, const float* __restrict__ b2,
    const float* __restrict__ lns_w, const float* __restrict__ lns_b,
    const float* __restrict__ Mt,
    float* __restrict__ slots, f16* __restrict__ qkpad,
    int do_gru, int do_q)
{
  __shared__ __align__(16) float ybuf [4][64];
  __shared__ __align__(16) float updv [4][64];
  __shared__ __align__(16) float prevv[4][64];
  __shared__ __align__(16) float mlnv [4][64];
  __shared__ __align__(16) float sn2  [4][64];
  __shared__ __align__(16) float hbuf [4][128];
  const int w = threadIdx.x >> 6, d = threadIdx.x & 63;
  const int wid = blockIdx.x*4 + w;             // 0..895
  const int b = wid / 7, s = wid - b*7;

  float out;
  if (do_gru) {
    float yv  = acc_rd[(b*8+s)*64 + d];
    float cs  = cs_rd[b*16 + s];
    float prev = slots[(b*7+s)*64 + d];
    ybuf[w][d] = yv;
    LGKM0(); CBAR();
    float up = 0.f;
    #pragma unroll
    for (int jc = 0; jc < 16; jc++)
      up += dot4(*(const f32x4*)(Wv + d*64 + jc*4),
                 *(const f32x4*)&ybuf[w][jc*4]);
    float upd = up / cs;
    updv[w][d] = upd; prevv[w][d] = prev;
    LGKM0(); CBAR();

    float air = b_ih[d], aiz = b_ih[64+d], ain = b_ih[128+d];
    float ahr = b_hh[d], ahz = b_hh[64+d], ahn = b_hh[128+d];
    #pragma unroll
    for (int jc = 0; jc < 16; jc++) {
      f32x4 u = *(const f32x4*)&updv[w][jc*4];
      f32x4 p = *(const f32x4*)&prevv[w][jc*4];
      air += dot4(*(const f32x4*)(W_ih + d*64       + jc*4), u);
      aiz += dot4(*(const f32x4*)(W_ih + (64+d)*64  + jc*4), u);
      ain += dot4(*(const f32x4*)(W_ih + (128+d)*64 + jc*4), u);
      ahr += dot4(*(const f32x4*)(W_hh + d*64       + jc*4), p);
      ahz += dot4(*(const f32x4*)(W_hh + (64+d)*64  + jc*4), p);
      ahn += dot4(*(const f32x4*)(W_hh + (128+d)*64 + jc*4), p);
    }
    float r = 1.f/(1.f + __expf(-(air+ahr)));
    float z = 1.f/(1.f + __expf(-(aiz+ahz)));
    float n = tanhf(ain + r*ahn);
    float hnew = (1.f - z)*n + z*prev;

    float s1 = hnew, s2 = hnew*hnew;
    #pragma unroll
    for (int m = 1; m < 64; m <<= 1) {
      s1 += __shfl_xor(s1, m, 64);
      s2 += __shfl_xor(s2, m, 64);
    }
    float mean = s1*(1.f/64.f), var = s2*(1.f/64.f) - mean*mean;
    float mln = (hnew - mean) * rsqrtf(var + 1e-5f) * lnm_w[d] + lnm_b[d];
    mlnv[w][d] = mln;
    LGKM0(); CBAR();

    float h0 = b1[d], h1 = b1[64+d];
    #pragma unroll
    for (int jc = 0; jc < 16; jc++) {
      f32x4 m4 = *(const f32x4*)&mlnv[w][jc*4];
      h0 += dot4(*(const f32x4*)(W1 + d*64      + jc*4), m4);
      h1 += dot4(*(const f32x4*)(W1 + (64+d)*64 + jc*4), m4);
    }
    h0 = fmaxf(h0, 0.f); h1 = fmaxf(h1, 0.f);
    hbuf[w][d] = h0; hbuf[w][64+d] = h1;
    LGKM0(); CBAR();

    out = hnew + b2[d];
    #pragma unroll
    for (int hc = 0; hc < 32; hc++)
      out += dot4(*(const f32x4*)(W2 + d*128 + hc*4),
                  *(const f32x4*)&hbuf[w][hc*4]);
    slots[(b*7+s)*64 + d] = out;
  } else {
    out = slots[(b*7+s)*64 + d];
  }

  if (do_q) {
    float s1 = out, s2 = out*out;
    #pragma unroll
    for (int m = 1; m < 64; m <<= 1) {
      s1 += __shfl_xor(s1, m, 64);
      s2 += __shfl_xor(s2, m, 64);
    }
    float mean = s1*(1.f/64.f), var = s2*(1.f/64.f) - mean*mean;
    float sv = (out - mean) * rsqrtf(var + 1e-5f) * lns_w[d] + lns_b[d];
    sn2[w][d] = sv;
    LGKM0(); CBAR();

    float qk = 0.f;
    #pragma unroll
    for (int jc = 0; jc < 16; jc++)
      qk += dot4(*(const f32x4*)(Mt + d*64 + jc*4),
                 *(const f32x4*)&sn2[w][jc*4]);
    qkpad[(b*16+s)*64 + d] = (f16)qk;

    if (s == 0) {
      #pragma unroll
      for (int r = 7; r < 16; r++) qkpad[(b*16+r)*64 + d] = (f16)0.f;
      #pragma unroll
      for (int r = 0; r < 8; r++)  acc_zw[(b*8+r)*64 + d] = 0.f;
      if (d < 16) cs_zw[b*16 + d] = 0.f;
    }
  }
}

// ---------------------------------------------------------------- k_attn ----
// grid (16,128): y=b, x=256-token chunk. 4 waves x 64 tokens (4 tiles of 16).
// Per tile: logits L^T (2 MFMA) -> exp -> butterfly sum over 16 lanes ->
// P (= 16x16x16 A-frag, in regs) ; x^T B-frags via 4 selector-MFMAs ;
// 4 PV MFMAs accumulate Y[slot][dim]. End: LDS reduce + global atomics.
static __device__ __forceinline__ void tile_step(
    f16x8 xf0, f16x8 xf1, const f16x8* qkB, f16x8 selLo, f16x8 selHi,
    f32x4* acc, float& csump, int c)
{
  const f32x4 zero4 = {0.f,0.f,0.f,0.f};
  f32x4 lg = zero4;
  lg = MFMA32(xf0, qkB[0], lg);
  lg = MFMA32(xf1, qkB[1], lg);
  const bool valid = (c < 7);
  float e[4], sm[4];
  #pragma unroll
  for (int r = 0; r < 4; r++) {
    e[r] = valid ? __expf(lg[r]) : 0.f;   // no max-sub: |logits| ~ O(6)
    sm[r] = e[r];
  }
  #pragma unroll
  for (int m = 1; m < 16; m <<= 1)
    #pragma unroll
    for (int r = 0; r < 4; r++) sm[r] += __shfl_xor(sm[r], m, 64);
  f16x4 pp;
  #pragma unroll
  for (int r = 0; r < 4; r++) {
    float p = valid ? (e[r]/sm[r] + 1e-8f) : 0.f;
    f16 ph = (f16)p;
    csump += (float)ph;                   // consistent with fp16 P in PV
    pp[r] = ph;
  }
  f16x4 xtB[4];
  #pragma unroll
  for (int nb = 0; nb < 4; nb++) {
    f32x4 tr = MFMA32(nb < 2 ? xf0 : xf1, (nb & 1) ? selHi : selLo, zero4);
    f16x4 xt; xt.x=(f16)tr.x; xt.y=(f16)tr.y; xt.z=(f16)tr.z; xt.w=(f16)tr.w;
    xtB[nb] = xt;
  }
  #pragma unroll
  for (int nb = 0; nb < 4; nb++)
    acc[nb] = MFMA16(pp, xtB[nb], acc[nb]);
}

template<int ITER0>
__global__ __launch_bounds__(256, 4) void k_attn_t(
    const float* __restrict__ x_in, f16* __restrict__ xln,
    const f16* __restrict__ qkpad,
    const float* __restrict__ lnw, const float* __restrict__ lnb,
    float* __restrict__ acc_g, float* __restrict__ cs_g)
{
  __shared__ __align__(16) float accbuf[1024];
  __shared__ float csl[16];
  const int b = blockIdx.y, cx = blockIdx.x;
  const int tid = threadIdx.x;
  const int lane = tid & 63, q = lane >> 4, c = lane & 15;
  const int w = tid >> 6;

  #pragma unroll
  for (int p = 0; p < 4; p++) accbuf[p*256 + tid] = 0.f;
  if (tid < 16) csl[tid] = 0.f;
  __syncthreads();

  f16x8 qkB[2];
  #pragma unroll
  for (int h = 0; h < 2; h++)
    qkB[h] = *(const f16x8*)(qkpad + (b*16+c)*64 + h*32 + q*8);

  f16x8 selLo, selHi;
  #pragma unroll
  for (int j = 0; j < 8; j++) {
    selLo[j] = (f16)((( c>>3)    == q && (c&7) == j) ? 1.0f : 0.0f);
    selHi[j] = (f16)(((c>>3) + 2 == q && (c&7) == j) ? 1.0f : 0.0f);
  }

  const f32x4 zero4 = {0.f,0.f,0.f,0.f};
  f32x4 acc[4] = {zero4, zero4, zero4, zero4};
  float csump = 0.f;
  const size_t tok0 = (size_t)b*Nn + (size_t)cx*256 + (size_t)w*64;

  if constexpr (ITER0) {
    f32x4 wv[4], bv[4];
    wv[0] = *(const f32x4*)(lnw + q*8);      wv[1] = *(const f32x4*)(lnw + q*8 + 4);
    wv[2] = *(const f32x4*)(lnw + 32 + q*8); wv[3] = *(const f32x4*)(lnw + 32 + q*8 + 4);
    bv[0] = *(const f32x4*)(lnb + q*8);      bv[1] = *(const f32x4*)(lnb + q*8 + 4);
    bv[2] = *(const f32x4*)(lnb + 32 + q*8); bv[3] = *(const f32x4*)(lnb + 32 + q*8 + 4);

    f32x4 xr[2][4];
    {
      const float* base = x_in + (tok0 + c)*64;
      xr[0][0] = *(const f32x4*)(base + q*8);
      xr[0][1] = *(const f32x4*)(base + q*8 + 4);
      xr[0][2] = *(const f32x4*)(base + 32 + q*8);
      xr[0][3] = *(const f32x4*)(base + 32 + q*8 + 4);
    }
    #pragma unroll
    for (int t = 0; t < 4; t++) {
      const int cur = t & 1;
      if (t < 3) {
        const float* base = x_in + (tok0 + (t+1)*16 + c)*64;
        xr[cur^1][0] = *(const f32x4*)(base + q*8);
        xr[cur^1][1] = *(const f32x4*)(base + q*8 + 4);
        xr[cur^1][2] = *(const f32x4*)(base + 32 + q*8);
        xr[cur^1][3] = *(const f32x4*)(base + 32 + q*8 + 4);
      }
      f32x4 a0 = xr[cur][0], a1 = xr[cur][1], a2 = xr[cur][2], a3 = xr[cur][3];
      float s1 = (a0.x+a0.y+a0.z+a0.w) + (a1.x+a1.y+a1.z+a1.w)
               + (a2.x+a2.y+a2.z+a2.w) + (a3.x+a3.y+a3.z+a3.w);
      float s2 = dot4(a0,a0) + dot4(a1,a1) + dot4(a2,a2) + dot4(a3,a3);
      s1 += __shfl_xor(s1, 16, 64); s1 += __shfl_xor(s1, 32, 64);
      s2 += __shfl_xor(s2, 16, 64); s2 += __shfl_xor(s2, 32, 64);
      float mean = s1*(1.f/64.f);
      float rstd = rsqrtf(s2*(1.f/64.f) - mean*mean + 1e-5f);
      f16x8 x0, x1;
      #pragma unroll
      for (int j = 0; j < 4; j++) {
        x0[j]   = (f16)((a0[j]-mean)*rstd*wv[0][j] + bv[0][j]);
        x0[4+j] = (f16)((a1[j]-mean)*rstd*wv[1][j] + bv[1][j]);
        x1[j]   = (f16)((a2[j]-mean)*rstd*wv[2][j] + bv[2][j]);
        x1[4+j] = (f16)((a3[j]-mean)*rstd*wv[3][j] + bv[3][j]);
      }
      f16* xo = xln + (tok0 + t*16 + c)*64;
      *(f16x8*)(xo + q*8)      = x0;
      *(f16x8*)(xo + 32 + q*8) = x1;
      tile_step(x0, x1, qkB, selLo, selHi, acc, csump, c);
    }
  } else {
    f16x8 xf[4][2];
    #pragma unroll
    for (int t = 0; t < 4; t++)
      #pragma unroll
      for (int h = 0; h < 2; h++)
        xf[t][h] = *(const f16x8*)(xln + (tok0 + t*16 + c)*64 + h*32 + q*8);
    #pragma unroll
    for (int t = 0; t < 4; t++)
      tile_step(xf[t][0], xf[t][1], qkB, selLo, selHi, acc, csump, c);
  }

  // csum: butterfly over quads -> full per-slot sum in every lane
  csump += __shfl_xor(csump, 16, 64);
  csump += __shfl_xor(csump, 32, 64);
  if (lane < 7)
    __hip_atomic_fetch_add(&csl[lane], csump,
                           __ATOMIC_RELAXED, __HIP_MEMORY_SCOPE_WORKGROUP);
  #pragma unroll
  for (int nb = 0; nb < 4; nb++)
    #pragma unroll
    for (int r = 0; r < 4; r++)
      __hip_atomic_fetch_add(&accbuf[(q*4+r)*64 + nb*16 + c], acc[nb][r],
                             __ATOMIC_RELAXED, __HIP_MEMORY_SCOPE_WORKGROUP);
  __syncthreads();
  #pragma unroll
  for (int p = 0; p < 2; p++)     // slots 0..7 only (8..15 are zero)
    __hip_atomic_fetch_add(&acc_g[b*512 + p*256 + tid], accbuf[p*256 + tid],
                           __ATOMIC_RELAXED, __HIP_MEMORY_SCOPE_AGENT);
  if (tid < 7)
    __hip_atomic_fetch_add(&cs_g[b*16 + tid], csl[tid],
                           __ATOMIC_RELAXED, __HIP_MEMORY_SCOPE_AGENT);
}

// ----------------------------------------------------------- kernel_launch --
extern "C" void kernel_launch(void* const* d_in, const int* in_sizes, int n_in,
                              void* d_out, int out_size, void* d_ws, size_t ws_size,
                              hipStream_t stream) {
  const float* inputs  = (const float*)d_in[0];
  const float* noise   = (const float*)d_in[1];
  const float* ln_in_w = (const float*)d_in[2];
  const float* ln_in_b = (const float*)d_in[3];
  const float* ln_sl_w = (const float*)d_in[4];
  const float* ln_sl_b = (const float*)d_in[5];
  const float* ln_ml_w = (const float*)d_in[6];
  const float* ln_ml_b = (const float*)d_in[7];
  const float* mu   = (const float*)d_in[8];
  const float* ls   = (const float*)d_in[9];
  const float* Wq   = (const float*)d_in[10];
  const float* Wk   = (const float*)d_in[11];
  const float* Wv   = (const float*)d_in[12];
  const float* W_ih = (const float*)d_in[13];
  const float* W_hh = (const float*)d_in[14];
  const float* b_ih = (const float*)d_in[15];
  const float* b_hh = (const float*)d_in[16];
  const float* W1 = (const float*)d_in[17];
  const float* b1 = (const float*)d_in[18];
  const float* W2 = (const float*)d_in[19];
  const float* b2 = (const float*)d_in[20];

  float* slots = (float*)d_out;

  const size_t XLN_OFF  = 0;                    // fp16 [B,N,64] = 64 MiB
  const size_t QK_OFF   = 67108864;             // fp16 [B,16,64]
  const size_t ACC0_OFF = QK_OFF   + 262144;    // fp32 [B,8,64]
  const size_t ACC1_OFF = ACC0_OFF + 262144;
  const size_t CS0_OFF  = ACC1_OFF + 262144;    // fp32 [B,16]
  const size_t CS1_OFF  = CS0_OFF  + 8192;
  const size_t MT_OFF   = CS1_OFF  + 8192;      // fp32 [64,64]
  const size_t NEED     = MT_OFF   + 16384;
  if (ws_size < NEED) return;

  char* ws = (char*)d_ws;
  f16*   xln  = (f16*)(ws + XLN_OFF);
  f16*   qk   = (f16*)(ws + QK_OFF);
  float* acc0 = (float*)(ws + ACC0_OFF);
  float* acc1 = (float*)(ws + ACC1_OFF);
  float* cs0  = (float*)(ws + CS0_OFF);
  float* cs1  = (float*)(ws + CS1_OFF);
  float* Mt   = (float*)(ws + MT_OFF);

  float* accR[4] = {acc0, acc1, acc0, acc1};
  float* csR [4] = {cs0,  cs1,  cs0,  cs1};

  k_init<<<240, 256, 0, stream>>>(noise, mu, ls, Wq, Wk, slots, Mt);
  // initial: compute qk for iter0, zero acc0/cs0
  k_gru<<<224, 256, 0, stream>>>(acc0, cs0, acc0, cs0, Wv,
                                 W_ih, W_hh, b_ih, b_hh, ln_ml_w, ln_ml_b,
                                 W1, b1, W2, b2, ln_sl_w, ln_sl_b, Mt,
                                 slots, qk, 0, 1);
  dim3 ga(16, 128);
  for (int it = 0; it < 3; it++) {
    if (it == 0)
      k_attn_t<1><<<ga, 256, 0, stream>>>(inputs, xln, qk, ln_in_w, ln_in_b,
                                          accR[it], csR[it]);
    else
      k_attn_t<0><<<ga, 256, 0, stream>>>(inputs, xln, qk, ln_in_w, ln_in_b,
                                          accR[it], csR[it]);
    // reads buf[it], zeroes buf[it+1] (the one attn(it+1) accumulates into)
    k_gru<<<224, 256, 0, stream>>>(accR[it], csR[it], accR[it+1], csR[it+1], Wv,
                                   W_ih, W_hh, b_ih, b_hh, ln_ml_w, ln_ml_b,
                                   W1, b1, W2, b2, ln_sl_w, ln_sl_b, Mt,
                                   slots, qk, 1, it < 2 ? 1 : 0);
  }
}

// Round 6
// 362.005 us; speedup vs baseline: 1.3601x; 1.2410x over previous
//
#include <hip/hip_runtime.h>

// SlotAttention MI355X (gfx950), round 6 = round 5 + partial-store fix
// (256-thread block must cover all 7x64 partial entries; R5 wrote rows 0..3
// only, leaving slots 4..6 poisoned).
// - No device atomics: attn writes per-block partials, gru sums them.
// - LN folded algebraically; attn reads raw fp32 inputs every iteration:
//     logits[t][s] = r_t*(x[t].qkw[s]) + beta[s] - (m_t r_t)*gamma[s]
//     PRX[s][d]    = sum_t p*r_t*x[t][d]   (MFMA, selector-transpose PV)
//     alpha[s]=sum p ; delta[s]=sum p*m_t*r_t
//   gru: upd[d] = lnw_in[d]*(PRX[d]-delta)/alpha + lnb_in[d] ; then @Wv^T.
// - k_gru: weights staged per 64x64 chunk in LDS (coalesced), dots from LDS.

#define Nn 4096

typedef _Float16 f16;
typedef _Float16 f16x8 __attribute__((ext_vector_type(8)));
typedef _Float16 f16x4 __attribute__((ext_vector_type(4)));
typedef float    f32x4 __attribute__((ext_vector_type(4)));

#define MFMA16(a,b,c) __builtin_amdgcn_mfma_f32_16x16x16f16(a,b,c,0,0,0)
#define MFMA32(a,b,c) __builtin_amdgcn_mfma_f32_16x16x32_f16(a,b,c,0,0,0)
#define LGKM0() asm volatile("s_waitcnt lgkmcnt(0)" ::: "memory")

static __device__ __forceinline__ float dot4(f32x4 a, f32x4 b) {
  return a.x*b.x + a.y*b.y + a.z*b.z + a.w*b.w;
}

// ---------------------------------------------------------------- k_init ----
// blocks 0..55: slots = mu + exp(log_sigma)*noise (57344 floats, 1024/block)
// blocks 56..71: Mt[d][e] = 0.125 * sum_dd Wk[dd][d]*Wq[dd][e]  (fp32)
__global__ __launch_bounds__(256) void k_init(
    const float* __restrict__ noise, const float* __restrict__ mu,
    const float* __restrict__ ls, const float* __restrict__ Wq,
    const float* __restrict__ Wk, float* __restrict__ slots,
    float* __restrict__ Mt)
{
  int bk = blockIdx.x, t = threadIdx.x;
  if (bk < 56) {
    int i = bk*1024 + t*4;
    int d = i & 63;
    f32x4 nz = *(const f32x4*)(noise + i);
    f32x4 m4 = *(const f32x4*)(mu + d);
    f32x4 l4 = *(const f32x4*)(ls + d);
    f32x4 o;
    o.x = m4.x + expf(l4.x)*nz.x; o.y = m4.y + expf(l4.y)*nz.y;
    o.z = m4.z + expf(l4.z)*nz.z; o.w = m4.w + expf(l4.w)*nz.w;
    *(f32x4*)(slots + i) = o;
  } else {
    int idx = (bk-56)*256 + t;         // 0..4095
    int d = idx >> 6, e = idx & 63;
    float a = 0.f;
    for (int dd = 0; dd < 64; dd++)
      a += Wk[dd*64 + d] * Wq[dd*64 + e];
    Mt[idx] = a * 0.125f;              // fold scale = D^-0.5
  }
}

// ----------------------------------------------------------------- k_gru ----
// 224 blocks x 256 (4 waves, wave = one (b,s) row). Weight chunks (64x64)
// staged in LDS coalesced; per-lane dots read LDS rows (stride 68).
static __device__ __forceinline__ void stage_chunk(
    float (*Wl)[68], const float* __restrict__ src, int stride, int t)
{
  __syncthreads();                 // protect previous consumers of Wl
  int r = t >> 2, c4 = (t & 3) * 16;
  #pragma unroll
  for (int k = 0; k < 4; k++)
    *(f32x4*)&Wl[r][c4 + k*4] = *(const f32x4*)(src + (size_t)r*stride + c4 + k*4);
  __syncthreads();
}

static __device__ __forceinline__ float dot_row(
    float (*Wl)[68], int d, const float* v)
{
  float a = 0.f;
  #pragma unroll
  for (int jc = 0; jc < 16; jc++)
    a += dot4(*(const f32x4*)&Wl[d][jc*4], *(const f32x4*)(v + jc*4));
  return a;
}

__global__ __launch_bounds__(256) void k_gru(
    const float* __restrict__ part, const float* __restrict__ csp,
    const float* __restrict__ lnw_in, const float* __restrict__ lnb_in,
    const float* __restrict__ Wv,
    const float* __restrict__ W_ih, const float* __restrict__ W_hh,
    const float* __restrict__ b_ih, const float* __restrict__ b_hh,
    const float* __restrict__ lnm_w, const float* __restrict__ lnm_b,
    const float* __restrict__ W1, const float* __restrict__ b1,
    const float* __restrict__ W2, const float* __restrict__ b2,
    const float* __restrict__ lns_w, const float* __restrict__ lns_b,
    const float* __restrict__ Mt,
    float* __restrict__ slots, f16* __restrict__ qkpad,
    float* __restrict__ qkaux, int do_gru, int do_q)
{
  __shared__ __align__(16) float Wl[64][68];
  __shared__ __align__(16) float updv[4][64];
  __shared__ __align__(16) float u2v [4][64];
  __shared__ __align__(16) float prevv[4][64];
  __shared__ __align__(16) float mlnv[4][64];
  __shared__ __align__(16) float sn2 [4][64];
  __shared__ __align__(16) float hbuf[4][128];
  const int t = threadIdx.x, w = t >> 6, d = t & 63;
  const int wid = blockIdx.x*4 + w;             // 0..895
  const int b = wid / 7, s = wid - b*7;

  float out;
  if (do_gru) {
    // Y = sum of 8 chunk partials ; alpha/delta from csp
    float Y = 0.f, alpha = 0.f, delta = 0.f;
    #pragma unroll
    for (int cx = 0; cx < 8; cx++) {
      Y     += part[(((size_t)b*8+cx)*8 + s)*64 + d];
      alpha += csp [(((size_t)b*8+cx)*8 + s)*2 + 0];
      delta += csp [(((size_t)b*8+cx)*8 + s)*2 + 1];
    }
    float upd_pre = lnw_in[d]*(Y - delta)/alpha + lnb_in[d];
    float prev = slots[(size_t)wid*64 + d];
    updv[w][d] = upd_pre; prevv[w][d] = prev;
    LGKM0();

    stage_chunk(Wl, Wv, 64, t);
    u2v[w][d] = dot_row(Wl, d, updv[w]);        // updates = upd_pre @ Wv^T
    LGKM0();

    stage_chunk(Wl, W_ih,         64, t);
    float air = b_ih[d]     + dot_row(Wl, d, u2v[w]);
    stage_chunk(Wl, W_ih + 4096,  64, t);
    float aiz = b_ih[64+d]  + dot_row(Wl, d, u2v[w]);
    stage_chunk(Wl, W_ih + 8192,  64, t);
    float ain = b_ih[128+d] + dot_row(Wl, d, u2v[w]);
    stage_chunk(Wl, W_hh,         64, t);
    float ahr = b_hh[d]     + dot_row(Wl, d, prevv[w]);
    stage_chunk(Wl, W_hh + 4096,  64, t);
    float ahz = b_hh[64+d]  + dot_row(Wl, d, prevv[w]);
    stage_chunk(Wl, W_hh + 8192,  64, t);
    float ahn = b_hh[128+d] + dot_row(Wl, d, prevv[w]);

    float r = 1.f/(1.f + __expf(-(air+ahr)));
    float z = 1.f/(1.f + __expf(-(aiz+ahz)));
    float n = tanhf(ain + r*ahn);
    float hnew = (1.f - z)*n + z*prev;

    float s1 = hnew, s2 = hnew*hnew;
    #pragma unroll
    for (int m = 1; m < 64; m <<= 1) {
      s1 += __shfl_xor(s1, m, 64);
      s2 += __shfl_xor(s2, m, 64);
    }
    float mean = s1*(1.f/64.f), var = s2*(1.f/64.f) - mean*mean;
    float mln = (hnew - mean) * rsqrtf(var + 1e-5f) * lnm_w[d] + lnm_b[d];
    mlnv[w][d] = mln;
    LGKM0();

    stage_chunk(Wl, W1,        64, t);
    float h0 = fmaxf(b1[d]    + dot_row(Wl, d, mlnv[w]), 0.f);
    stage_chunk(Wl, W1 + 4096, 64, t);
    float h1 = fmaxf(b1[64+d] + dot_row(Wl, d, mlnv[w]), 0.f);
    hbuf[w][d] = h0; hbuf[w][64+d] = h1;
    LGKM0();

    stage_chunk(Wl, W2,      128, t);
    out = hnew + b2[d] + dot_row(Wl, d, hbuf[w]);
    stage_chunk(Wl, W2 + 64, 128, t);
    out += dot_row(Wl, d, hbuf[w] + 64);
    slots[(size_t)wid*64 + d] = out;
  } else {
    out = slots[(size_t)wid*64 + d];
  }

  if (do_q) {
    float s1 = out, s2 = out*out;
    #pragma unroll
    for (int m = 1; m < 64; m <<= 1) {
      s1 += __shfl_xor(s1, m, 64);
      s2 += __shfl_xor(s2, m, 64);
    }
    float mean = s1*(1.f/64.f), var = s2*(1.f/64.f) - mean*mean;
    float sv = (out - mean) * rsqrtf(var + 1e-5f) * lns_w[d] + lns_b[d];
    sn2[w][d] = sv;
    LGKM0();

    stage_chunk(Wl, Mt, 64, t);
    float qk = dot_row(Wl, d, sn2[w]);          // qk = sv @ Mt^T (scale folded)

    float qw = qk * lnw_in[d];                  // qkw for logits MFMA
    float bb = qk * lnb_in[d];                  // -> beta
    float gg = qw;                              // -> gamma
    #pragma unroll
    for (int m = 1; m < 64; m <<= 1) {
      bb += __shfl_xor(bb, m, 64);
      gg += __shfl_xor(gg, m, 64);
    }
    qkpad[((size_t)b*16 + s)*64 + d] = (f16)qw;
    if (d == 0) {
      qkaux[((size_t)b*16 + s)*2 + 0] = bb;
      qkaux[((size_t)b*16 + s)*2 + 1] = gg;
    }
  }
}

// ---------------------------------------------------------------- k_attn ----
// grid (8,128): y=b, x=512-token chunk. 4 waves x 128 tokens (8 tiles of 16).
// Reads raw fp32 inputs. Per tile: token stats (4+8 shuffles) -> raw logits
// MFMA -> affine fixup -> softmax -> P*r -> selector-transpose PV (all regs).
// Ends with NON-ATOMIC per-block partial stores (all 7x64 entries, strided).
__global__ __launch_bounds__(256, 4) void k_attn(
    const float* __restrict__ x_in, const f16* __restrict__ qkpad,
    const float* __restrict__ qkaux,
    float* __restrict__ part, float* __restrict__ csp)
{
  __shared__ __align__(16) float accb[4][8][64];
  __shared__ float ldsc[4][8][2];
  const int b = blockIdx.y, cx = blockIdx.x;
  const int tid = threadIdx.x;
  const int w = tid >> 6, lane = tid & 63, q = lane >> 4, c = lane & 15;

  f16x8 qkB[2];
  qkB[0] = *(const f16x8*)(qkpad + ((size_t)b*16 + c)*64 + q*8);
  qkB[1] = *(const f16x8*)(qkpad + ((size_t)b*16 + c)*64 + 32 + q*8);
  const float beta  = qkaux[((size_t)b*16 + c)*2 + 0];
  const float gamma = qkaux[((size_t)b*16 + c)*2 + 1];

  f16x8 selLo, selHi;
  #pragma unroll
  for (int j = 0; j < 8; j++) {
    selLo[j] = (f16)((( c>>3)    == q && (c&7) == j) ? 1.0f : 0.0f);
    selHi[j] = (f16)(((c>>3) + 2 == q && (c&7) == j) ? 1.0f : 0.0f);
  }

  const f32x4 zero4 = {0.f,0.f,0.f,0.f};
  f32x4 acc[4] = {zero4, zero4, zero4, zero4};
  float csump = 0.f, dsump = 0.f;
  const size_t tok0 = (size_t)b*Nn + (size_t)cx*512 + (size_t)w*128;
  const bool valid = (c < 7);

  // prefetch tile 0 (token c, dims q*8..+7 and 32+q*8..+7)
  f32x4 nx[4];
  {
    const float* base = x_in + (tok0 + c)*64;
    nx[0] = *(const f32x4*)(base + q*8);
    nx[1] = *(const f32x4*)(base + q*8 + 4);
    nx[2] = *(const f32x4*)(base + 32 + q*8);
    nx[3] = *(const f32x4*)(base + 32 + q*8 + 4);
  }

  #pragma unroll
  for (int t = 0; t < 8; t++) {
    f32x4 xv[4];
    #pragma unroll
    for (int i = 0; i < 4; i++) xv[i] = nx[i];
    if (t < 7) {
      const float* base = x_in + (tok0 + (t+1)*16 + c)*64;
      nx[0] = *(const f32x4*)(base + q*8);
      nx[1] = *(const f32x4*)(base + q*8 + 4);
      nx[2] = *(const f32x4*)(base + 32 + q*8);
      nx[3] = *(const f32x4*)(base + 32 + q*8 + 4);
    }
    // token-c stats over 64 dims (4 lanes share token c)
    float sx  = (xv[0].x+xv[0].y+xv[0].z+xv[0].w) + (xv[1].x+xv[1].y+xv[1].z+xv[1].w)
              + (xv[2].x+xv[2].y+xv[2].z+xv[2].w) + (xv[3].x+xv[3].y+xv[3].z+xv[3].w);
    float sxx = dot4(xv[0],xv[0]) + dot4(xv[1],xv[1])
              + dot4(xv[2],xv[2]) + dot4(xv[3],xv[3]);
    sx  += __shfl_xor(sx, 16, 64);  sx  += __shfl_xor(sx, 32, 64);
    sxx += __shfl_xor(sxx, 16, 64); sxx += __shfl_xor(sxx, 32, 64);
    float mean = sx*(1.f/64.f);
    float rstd = rsqrtf(sxx*(1.f/64.f) - mean*mean + 1e-5f);
    float mr = mean * rstd;
    // transpose stats: reg j's token is q*4+j
    float rT[4], mT[4];
    #pragma unroll
    for (int j = 0; j < 4; j++) {
      rT[j] = __shfl(rstd, q*4 + j, 64);
      mT[j] = __shfl(mr,   q*4 + j, 64);
    }
    // fp16 frags of raw x
    f16x8 xf0, xf1;
    #pragma unroll
    for (int j = 0; j < 4; j++) {
      xf0[j] = (f16)xv[0][j]; xf0[4+j] = (f16)xv[1][j];
      xf1[j] = (f16)xv[2][j]; xf1[4+j] = (f16)xv[3][j];
    }
    // raw logits + affine LN fixup
    f32x4 lg = zero4;
    lg = MFMA32(xf0, qkB[0], lg);
    lg = MFMA32(xf1, qkB[1], lg);
    float e[4], sm[4];
    #pragma unroll
    for (int j = 0; j < 4; j++) {
      float L = rT[j]*lg[j] + beta - mT[j]*gamma;
      e[j] = valid ? __expf(L) : 0.f;
      sm[j] = e[j];
    }
    #pragma unroll
    for (int m = 1; m < 16; m <<= 1)
      #pragma unroll
      for (int j = 0; j < 4; j++) sm[j] += __shfl_xor(sm[j], m, 64);
    f16x4 pp;
    #pragma unroll
    for (int j = 0; j < 4; j++) {
      float p = valid ? (e[j]/sm[j] + 1e-8f) : 0.f;
      csump += p;
      dsump += p * mT[j];
      pp[j] = (f16)(p * rT[j]);
    }
    // x^T B-frags via selector transpose; PV accumulate PRX
    #pragma unroll
    for (int nb = 0; nb < 4; nb++) {
      f32x4 tr = MFMA32(nb < 2 ? xf0 : xf1, (nb & 1) ? selHi : selLo, zero4);
      f16x4 xt; xt.x=(f16)tr.x; xt.y=(f16)tr.y; xt.z=(f16)tr.z; xt.w=(f16)tr.w;
      acc[nb] = MFMA16(pp, xt, acc[nb]);
    }
  }

  csump += __shfl_xor(csump, 16, 64); csump += __shfl_xor(csump, 32, 64);
  dsump += __shfl_xor(dsump, 16, 64); dsump += __shfl_xor(dsump, 32, 64);
  if (q == 0 && c < 7) { ldsc[w][c][0] = csump; ldsc[w][c][1] = dsump; }
  if (q < 2) {
    #pragma unroll
    for (int nb = 0; nb < 4; nb++)
      #pragma unroll
      for (int r = 0; r < 4; r++)
        accb[w][q*4 + r][nb*16 + c] = acc[nb][r];
  }
  __syncthreads();
  // FIX (R5 bug): 256 threads must cover all 7*64=448 partial entries.
  for (int rr = tid; rr < 448; rr += 256) {
    int row = rr >> 6, dd = rr & 63;
    float v = accb[0][row][dd] + accb[1][row][dd]
            + accb[2][row][dd] + accb[3][row][dd];
    part[(((size_t)b*8 + cx)*8 + row)*64 + dd] = v;
  }
  if (tid < 14) {
    int s = tid >> 1, k = tid & 1;
    csp[(((size_t)b*8 + cx)*8 + s)*2 + k] =
        ldsc[0][s][k] + ldsc[1][s][k] + ldsc[2][s][k] + ldsc[3][s][k];
  }
}

// ----------------------------------------------------------- kernel_launch --
extern "C" void kernel_launch(void* const* d_in, const int* in_sizes, int n_in,
                              void* d_out, int out_size, void* d_ws, size_t ws_size,
                              hipStream_t stream) {
  const float* inputs  = (const float*)d_in[0];
  const float* noise   = (const float*)d_in[1];
  const float* ln_in_w = (const float*)d_in[2];
  const float* ln_in_b = (const float*)d_in[3];
  const float* ln_sl_w = (const float*)d_in[4];
  const float* ln_sl_b = (const float*)d_in[5];
  const float* ln_ml_w = (const float*)d_in[6];
  const float* ln_ml_b = (const float*)d_in[7];
  const float* mu   = (const float*)d_in[8];
  const float* ls   = (const float*)d_in[9];
  const float* Wq   = (const float*)d_in[10];
  const float* Wk   = (const float*)d_in[11];
  const float* Wv   = (const float*)d_in[12];
  const float* W_ih = (const float*)d_in[13];
  const float* W_hh = (const float*)d_in[14];
  const float* b_ih = (const float*)d_in[15];
  const float* b_hh = (const float*)d_in[16];
  const float* W1 = (const float*)d_in[17];
  const float* b1 = (const float*)d_in[18];
  const float* W2 = (const float*)d_in[19];
  const float* b2 = (const float*)d_in[20];

  float* slots = (float*)d_out;

  // workspace: part 2MB, csp 64KB, qkpad 256KB, qkaux 16KB, Mt 16KB
  const size_t PART_OFF = 0;                      // f32 [128][8][8][64]
  const size_t CSP_OFF  = PART_OFF + 2097152;     // f32 [128][8][8][2]
  const size_t QK_OFF   = CSP_OFF  + 65536;       // f16 [128][16][64]
  const size_t QA_OFF   = QK_OFF   + 262144;      // f32 [128][16][2]
  const size_t MT_OFF   = QA_OFF   + 16384;       // f32 [64][64]
  const size_t NEED     = MT_OFF   + 16384;
  if (ws_size < NEED) return;

  char* ws = (char*)d_ws;
  float* part  = (float*)(ws + PART_OFF);
  float* csp   = (float*)(ws + CSP_OFF);
  f16*   qkpad = (f16*)  (ws + QK_OFF);
  float* qkaux = (float*)(ws + QA_OFF);
  float* Mt    = (float*)(ws + MT_OFF);

  k_init<<<72, 256, 0, stream>>>(noise, mu, ls, Wq, Wk, slots, Mt);
  // initial q (no gru)
  k_gru<<<224, 256, 0, stream>>>(part, csp, ln_in_w, ln_in_b, Wv,
                                 W_ih, W_hh, b_ih, b_hh, ln_ml_w, ln_ml_b,
                                 W1, b1, W2, b2, ln_sl_w, ln_sl_b, Mt,
                                 slots, qkpad, qkaux, 0, 1);
  dim3 ga(8, 128);
  for (int it = 0; it < 3; it++) {
    k_attn<<<ga, 256, 0, stream>>>(inputs, qkpad, qkaux, part, csp);
    k_gru<<<224, 256, 0, stream>>>(part, csp, ln_in_w, ln_in_b, Wv,
                                   W_ih, W_hh, b_ih, b_hh, ln_ml_w, ln_ml_b,
                                   W1, b1, W2, b2, ln_sl_w, ln_sl_b, Mt,
                                   slots, qkpad, qkaux, 1, it < 2 ? 1 : 0);
  }
}